// Round 1
// baseline (1243.608 us; speedup 1.0000x reference)
//
#include <hip/hip_runtime.h>

#define WIDTH 128
#define NHID  3

typedef _Float16 v8h __attribute__((ext_vector_type(8)));
typedef float    v4f __attribute__((ext_vector_type(4)));

__device__ __forceinline__ float fast_tanh(float x) {
    float e = __expf(2.0f * x);
    return 1.0f - 2.0f / (e + 1.0f);
}

// ---------------------------------------------------------------------------
// Weight packing into B-fragment order for v_mfma_f32_16x16x32_f16.
// B element (k, n): k = 32*kk + 8*s + j  (s = lane>>4, j = 0..7), n = col.
// chunk = (kk*128 + n)*4 + (s ^ ((n>>1)&3))   [XOR spreads LDS banks]
// half stored at chunk*8 + j.
// Layout: [pipe(dp=0,ic=1)][layer(3)] x 16384 halves each.
// ---------------------------------------------------------------------------
__global__ void pack_weights(const float* __restrict__ dpWh,
                             const float* __restrict__ icWh,
                             _Float16* __restrict__ out) {
    int idx = blockIdx.x * 256 + threadIdx.x;
    if (idx >= 2 * NHID * WIDTH * WIDTH) return;
    int flat = idx & 16383;
    int j  = flat & 7;
    int sp = (flat >> 3) & 3;
    int n  = (flat >> 5) & 127;
    int kk = (flat >> 12) & 3;
    int lp = idx >> 14;               // 0..5
    int l  = lp % NHID;
    const float* src = (lp >= NHID) ? icWh : dpWh;
    int s = sp ^ ((n >> 1) & 3);
    int k = kk * 32 + s * 8 + j;
    out[idx] = (_Float16)src[(l * WIDTH + k) * WIDTH + n];
}

// LDS plan (dynamic shared, 139520 B):
//   [0,      65536)  wlds : dp hidden layers 0,1 fragment-packed (f16)
//   [65536, 131072)  act  : 4 waves x 64 rows x 128 f16 (chunk XOR-swizzled)
//   [131072,135168)  winb : [2][4][128] f32 input-layer weights (ic row3 = 0)
//   [135168,136192)  binb : [2][128] input biases
//   [136192,137216)  woutb: [2][128] output weights
//   [137216,138496)  rowb : [16][20] per-row geometry
//   [138496,139520)  cbuf : [4][64] per-eval-stream outputs
#define SMEM_BYTES 139520

__launch_bounds__(256, 1)
__global__ void node_main(const float* __restrict__ tx,
                          const float* __restrict__ dpWin, const float* __restrict__ dpBin,
                          const float* __restrict__ dpBh,  const float* __restrict__ dpWout,
                          const float* __restrict__ dpBout,
                          const float* __restrict__ icWin, const float* __restrict__ icBin,
                          const float* __restrict__ icBh,  const float* __restrict__ icWout,
                          const float* __restrict__ icBout,
                          const _Float16* __restrict__ pack,
                          float* __restrict__ outPot, float* __restrict__ outAcc,
                          int N)
{
    extern __shared__ char smem[];
    _Float16* wlds = (_Float16*)smem;
    _Float16* act  = (_Float16*)(smem + 65536);
    float* winb  = (float*)(smem + 131072);
    float* binb  = winb + 1024;
    float* woutb = binb + 256;
    float* rowb  = woutb + 256;
    float* cbuf  = rowb + 320;

    const int tid  = threadIdx.x;
    const int wave = tid >> 6;
    const int lane = tid & 63;

    // ---- stage weights ----
    for (int c = tid; c < 4096; c += 256)
        ((int4*)wlds)[c] = ((const int4*)pack)[c];
    for (int i = tid; i < 512; i += 256) {
        winb[i]       = dpWin[i];
        winb[512 + i] = (i < 384) ? icWin[i] : 0.0f;
    }
    if (tid < 128) {
        binb[tid]        = dpBin[tid];
        binb[128 + tid]  = icBin[tid];
        woutb[tid]       = dpWout[tid];
        woutb[128 + tid] = icWout[tid];
    }
    __syncthreads();

    _Float16* actw = act + wave * 8192;
    const float* bhp   = (wave == 3) ? icBh : dpBh;
    const float  boutv = (wave == 3) ? icBout[0] : dpBout[0];
    const int    woff  = (wave == 3) ? 512 : 0;
    const int    boff  = (wave == 3) ? 128 : 0;
    const int l15 = lane & 15;
    const int l4  = lane >> 4;

    // One hidden layer: 64 rows x 128 x 128, in-place on actw.
    auto run_layer = [&](const _Float16* bsrc, const float* bh) {
        v8h afr[4][4];
        #pragma unroll
        for (int m = 0; m < 4; m++) {
            #pragma unroll
            for (int kk = 0; kk < 4; kk++) {
                int slot = (kk * 4 + l4) ^ l15;
                afr[m][kk] = *(const v8h*)(actw + (m * 16 + l15) * 128 + slot * 8);
            }
        }
        v4f acc[4][8];
        #pragma unroll
        for (int nt = 0; nt < 8; nt++) {
            float bv = bh[nt * 16 + l15];
            #pragma unroll
            for (int m = 0; m < 4; m++) {
                v4f z = {bv, 0.0f, 0.0f, 0.0f};   // bias only on primal row (reg 0)
                acc[m][nt] = z;
            }
        }
        #pragma unroll
        for (int kk = 0; kk < 4; kk++) {
            #pragma unroll
            for (int nt = 0; nt < 8; nt++) {
                int n = nt * 16 + l15;
                int chunk = (kk * 128 + n) * 4 + (l4 ^ ((n >> 1) & 3));
                v8h bb = *(const v8h*)(bsrc + chunk * 8);
                #pragma unroll
                for (int m = 0; m < 4; m++)
                    acc[m][nt] = __builtin_amdgcn_mfma_f32_16x16x32_f16(afr[m][kk], bb, acc[m][nt], 0, 0, 0);
            }
        }
        #pragma unroll
        for (int m = 0; m < 4; m++) {
            #pragma unroll
            for (int nt = 0; nt < 8; nt++) {
                v4f v = acc[m][nt];
                int n  = nt * 16 + l15;
                int r0 = m * 16 + l4 * 4;
                float h = fast_tanh(v[0]);
                float D = 1.0f - h * h;
                int cj = n >> 3, nl = n & 7;
                actw[(r0    ) * 128 + ((cj ^ ((r0    ) & 15)) << 3) + nl] = (_Float16)h;
                actw[(r0 + 1) * 128 + ((cj ^ ((r0 + 1) & 15)) << 3) + nl] = (_Float16)(D * v[1]);
                actw[(r0 + 2) * 128 + ((cj ^ ((r0 + 2) & 15)) << 3) + nl] = (_Float16)(D * v[2]);
                actw[(r0 + 3) * 128 + ((cj ^ ((r0 + 3) & 15)) << 3) + nl] = (_Float16)(D * v[3]);
            }
        }
    };

    const int nbat = (N + 15) >> 4;
    for (int b = blockIdx.x; b < nbat; b += gridDim.x) {
        // ---- phase 1: per-row geometry (fp32, matches JAX autodiff formulas) ----
        if (wave == 0 && lane < 16) {
            int row = b * 16 + lane;
            float4 q = (row < N) ? ((const float4*)tx)[row] : make_float4(0.f, 1.f, 1.f, 1.f);
            float t = q.x, x = q.y, y = q.z, z = q.w;
            float r2 = x*x + y*y + z*z;
            float r  = sqrtf(r2 + 1e-12f);
            float rinv = 1.0f / r;
            float u  = z * rinv;
            float uc = fminf(1.0f, fmaxf(-1.0f, u));
            float th = acosf(uc);
            float ph = atan2f(y, x);
            float rinv3 = rinv * rinv * rinv;
            float omega = 1.0f - uc * uc;
            float dacos = -1.0f / sqrtf(fmaxf(omega, 1e-30f));
            float dth_dx = dacos * (-x * z * rinv3);
            float dth_dy = dacos * (-y * z * rinv3);
            float dth_dz = dacos * (rinv - z * z * rinv3);
            float rho2 = fmaxf(x*x + y*y, 1e-30f);
            float dph_dx = -y / rho2;
            float dph_dy =  x / rho2;
            float sEnv = -1.0f / (1.0f + r);
            float dsdr =  1.0f / ((1.0f + r) * (1.0f + r));
            float den  = r * r + 0.1f;
            float isq  = 1.0f / sqrtf(den);
            float Aan  = -isq;
            float dAdr = r * isq * isq * isq;
            float* rb = rowb + lane * 20;
            rb[0]=t;  rb[1]=r;  rb[2]=th; rb[3]=ph;
            rb[4]=x*rinv; rb[5]=y*rinv; rb[6]=z*rinv;
            rb[7]=dth_dx; rb[8]=dth_dy; rb[9]=dth_dz;
            rb[10]=dph_dx; rb[11]=dph_dy; rb[12]=0.0f;
            rb[13]=sEnv; rb[14]=dsdr; rb[15]=Aan; rb[16]=dAdr;
        }
        __syncthreads();

        // ---- phase 2: input layer fp32 + tangent seeding (unit tangents in xs) ----
        {
            const float* rb = rowb + l15 * 20;
            float t = rb[0], r = rb[1], th = rb[2], ph = rb[3];
            float in0, in1, in2, in3;
            int tshift;
            if (wave < 3) {
                float a = 0.5f * t;
                float node = (wave == 0) ? -0.7745966692414834f
                           : ((wave == 1) ? 0.0f : 0.7745966692414834f);
                in0 = a * node + 0.5f * t;  // ts_q
                in1 = r; in2 = th; in3 = ph;
                tshift = 1;                  // tangent rows use Win rows 1..3
            } else {
                in0 = r; in1 = th; in2 = ph; in3 = 0.0f;
                tshift = 0;                  // tangent rows use Win rows 0..2
            }
            const float* W  = winb + woff;
            const float* Bi = binb + boff;
            int r0 = 4 * l15;
            #pragma unroll 4
            for (int i = 0; i < 32; i++) {
                int n = (l4 << 5) + i;
                float w0 = W[n], w1 = W[128 + n], w2 = W[256 + n], w3 = W[384 + n];
                float pre = Bi[n] + in0 * w0 + in1 * w1 + in2 * w2 + in3 * w3;
                float h = fast_tanh(pre);
                float D = 1.0f - h * h;
                float ta = tshift ? w1 : w0;
                float tb = tshift ? w2 : w1;
                float tc = tshift ? w3 : w2;
                int cj = n >> 3, nl = n & 7;
                actw[(r0    ) * 128 + ((cj ^ ((r0    ) & 15)) << 3) + nl] = (_Float16)h;
                actw[(r0 + 1) * 128 + ((cj ^ ((r0 + 1) & 15)) << 3) + nl] = (_Float16)(D * ta);
                actw[(r0 + 2) * 128 + ((cj ^ ((r0 + 2) & 15)) << 3) + nl] = (_Float16)(D * tb);
                actw[(r0 + 3) * 128 + ((cj ^ ((r0 + 3) & 15)) << 3) + nl] = (_Float16)(D * tc);
            }
        }

        // ---- phase 3: three hidden 128x128 layers (MFMA f16) ----
        if (wave != 3) {
            run_layer(wlds,             bhp);
            run_layer(wlds + 16384,     bhp + 128);
            run_layer(pack + 2 * 16384, bhp + 256);
        } else {
            run_layer(pack + 3 * 16384, bhp);
            run_layer(pack + 4 * 16384, bhp + 128);
            run_layer(pack + 5 * 16384, bhp + 256);
        }

        // ---- phase 4: output dot (fp32) ----
        {
            const float* wo = woutb + boff;
            float sum = 0.0f;
            #pragma unroll
            for (int cj = 0; cj < 16; cj++) {
                v8h hv = *(const v8h*)(actw + lane * 128 + ((cj ^ l15) << 3));
                #pragma unroll
                for (int j = 0; j < 8; j++)
                    sum += (float)hv[j] * wo[cj * 8 + j];
            }
            if ((lane & 3) == 0) sum += boutv;   // bias on primal stream only
            cbuf[wave * 64 + lane] = sum;
        }
        __syncthreads();

        // ---- phase 5: quadrature + envelope + chain rule, write outputs ----
        if (wave == 0 && lane < 16) {
            int row = b * 16 + lane;
            if (row < N) {
                const float* rb = rowb + lane * 20;
                float t = rb[0];
                float a = 0.5f * t;
                float vic = cbuf[192 + (lane << 2) + 0];
                float g0  = cbuf[192 + (lane << 2) + 1];
                float g1  = cbuf[192 + (lane << 2) + 2];
                float g2  = cbuf[192 + (lane << 2) + 3];
                float dsum = 0.f, ds0 = 0.f, ds1 = 0.f, ds2 = 0.f;
                const float wq[3] = {0.5555555555555556f, 0.8888888888888889f, 0.5555555555555556f};
                #pragma unroll
                for (int qq = 0; qq < 3; qq++) {
                    float w = wq[qq];
                    dsum += w * cbuf[qq * 64 + (lane << 2) + 0];
                    ds0  += w * cbuf[qq * 64 + (lane << 2) + 1];
                    ds1  += w * cbuf[qq * 64 + (lane << 2) + 2];
                    ds2  += w * cbuf[qq * 64 + (lane << 2) + 3];
                }
                float tcv  = vic + a * dsum;
                float dtc0 = g0 + a * ds0, dtc1 = g1 + a * ds1, dtc2 = g2 + a * ds2;
                float sEnv = rb[13], dsdr = rb[14], Aan = rb[15], dAdr = rb[16];
                float pot = tcv * sEnv + Aan;
                float gx0 = sEnv * dtc0 + tcv * dsdr + dAdr;
                float gx1 = sEnv * dtc1;
                float gx2 = sEnv * dtc2;
                float ax = -(gx0 * rb[4] + gx1 * rb[7] + gx2 * rb[10]);
                float ay = -(gx0 * rb[5] + gx1 * rb[8] + gx2 * rb[11]);
                float az = -(gx0 * rb[6] + gx1 * rb[9] + gx2 * rb[12]);
                outPot[row] = pot;
                outAcc[row * 3 + 0] = ax;
                outAcc[row * 3 + 1] = ay;
                outAcc[row * 3 + 2] = az;
            }
        }
    }
}

extern "C" void kernel_launch(void* const* d_in, const int* in_sizes, int n_in,
                              void* d_out, int out_size, void* d_ws, size_t ws_size,
                              hipStream_t stream) {
    (void)n_in; (void)out_size;
    const float* tx     = (const float*)d_in[0];
    const float* dpWin  = (const float*)d_in[1];
    const float* dpBin  = (const float*)d_in[2];
    const float* dpWh   = (const float*)d_in[3];
    const float* dpBh   = (const float*)d_in[4];
    const float* dpWout = (const float*)d_in[5];
    const float* dpBout = (const float*)d_in[6];
    const float* icWin  = (const float*)d_in[7];
    const float* icBin  = (const float*)d_in[8];
    const float* icWh   = (const float*)d_in[9];
    const float* icBh   = (const float*)d_in[10];
    const float* icWout = (const float*)d_in[11];
    const float* icBout = (const float*)d_in[12];

    int N = in_sizes[0] / 4;
    if (ws_size < (size_t)(2 * NHID * WIDTH * WIDTH * sizeof(_Float16))) return;
    _Float16* pack = (_Float16*)d_ws;
    float* outPot = (float*)d_out;
    float* outAcc = outPot + N;

    pack_weights<<<(2 * NHID * WIDTH * WIDTH + 255) / 256, 256, 0, stream>>>(dpWh, icWh, pack);

    (void)hipFuncSetAttribute(reinterpret_cast<const void*>(node_main),
                              hipFuncAttributeMaxDynamicSharedMemorySize, SMEM_BYTES);
    node_main<<<256, 256, SMEM_BYTES, stream>>>(tx,
        dpWin, dpBin, dpBh, dpWout, dpBout,
        icWin, icBin, icBh, icWout, icBout,
        pack, outPot, outAcc, N);
}

// Round 2
// 729.368 us; speedup vs baseline: 1.7050x; 1.7050x over previous
//
#include <hip/hip_runtime.h>

typedef _Float16 v8h __attribute__((ext_vector_type(8)));
typedef float    v4f __attribute__((ext_vector_type(4)));

__device__ __forceinline__ float fast_tanh(float x) {
    float e = __expf(2.0f * x);
    return 1.0f - 2.0f / (e + 1.0f);
}

// ---------------------------------------------------------------------------
// pack layout (halves):
//  hidden: idx = ((((pipe*3+l)*4 + kk)*8 + nt)*64 + lane)*8 + j      [0, 98304)
//          value = Wh[l][k = kk*32 + (lane>>4)*8 + j][n = nt*16 + (lane&15)]
//  L0:     98304 + ((pipe*8 + nt)*64 + lane)*8 + j                   [98304, 106496)
//          value = Win[k = (lane>>4)*8+j][n] for k < in_dim else 0
// Lane-contiguous 16B per (kk,nt) block -> perfectly coalesced dwordx4 loads.
// ---------------------------------------------------------------------------
__global__ void pack_weights(const float* __restrict__ dpWh,
                             const float* __restrict__ icWh,
                             const float* __restrict__ dpWin,
                             const float* __restrict__ icWin,
                             _Float16* __restrict__ out) {
    int idx = blockIdx.x * 256 + threadIdx.x;
    if (idx < 98304) {
        int j    = idx & 7;
        int lane = (idx >> 3) & 63;
        int nt   = (idx >> 9) & 7;
        int kk   = (idx >> 12) & 3;
        int lp   = idx >> 14;           // 0..5
        int l    = lp % 3;
        const float* src = (lp >= 3) ? icWh : dpWh;
        int k = kk * 32 + (lane >> 4) * 8 + j;
        int n = nt * 16 + (lane & 15);
        out[idx] = (_Float16)src[(l * 128 + k) * 128 + n];
    } else if (idx < 106496) {
        int f    = idx - 98304;
        int j    = f & 7;
        int lane = (f >> 3) & 63;
        int nt   = (f >> 9) & 7;
        int pipe = (f >> 12) & 1;
        int k = (lane >> 4) * 8 + j;
        int n = nt * 16 + (lane & 15);
        float v = 0.0f;
        if (pipe == 0) { if (k < 4) v = dpWin[k * 128 + n]; }
        else           { if (k < 3) v = icWin[k * 128 + n]; }
        out[idx] = (_Float16)v;
    }
}

// LDS (dynamic, 72704 B -> 2 blocks/CU):
//   [0,     65536)  act : 4 waves x 64 rows x 128 halves, chunk-swizzled
//                   half idx(r,n) = r*128 + ((n>>3) ^ ((3*r)&15))*8 + (n&7)
//   [65536, 69632)  btab : float[2][4][128]  (layer biases: {Bin, Bh0..2} per pipe)
//   [69632, 70656)  woutb: float[2][128]
//   [70656, 72704)  cbuf : float[2][4][64]   (ping-pong by batch parity)
#define SMEM_BYTES 72704

__launch_bounds__(256, 2)
__global__ void node_main(const float* __restrict__ tx,
                          const float* __restrict__ dpBin, const float* __restrict__ dpBh,
                          const float* __restrict__ dpWout, const float* __restrict__ dpBout,
                          const float* __restrict__ icBin, const float* __restrict__ icBh,
                          const float* __restrict__ icWout, const float* __restrict__ icBout,
                          const _Float16* __restrict__ pack,
                          float* __restrict__ outPot, float* __restrict__ outAcc,
                          int N)
{
    extern __shared__ char smem[];
    _Float16* act  = (_Float16*)smem;
    float* btab  = (float*)(smem + 65536);
    float* woutb = (float*)(smem + 69632);
    float* cbuf  = (float*)(smem + 70656);

    const int tid  = threadIdx.x;
    const int wave = tid >> 6;
    const int lane = tid & 63;
    const int l15  = lane & 15;
    const int s    = lane >> 4;

    if (tid < 128) {
        btab[tid]       = dpBin[tid];
        btab[512 + tid] = icBin[tid];
        woutb[tid]       = dpWout[tid];
        woutb[128 + tid] = icWout[tid];
    }
    for (int i = tid; i < 384; i += 256) {
        btab[128 + i] = dpBh[i];
        btab[640 + i] = icBh[i];
    }
    __syncthreads();

    const bool isic = (wave == 3);
    const float node1 = (wave == 0) ? (1.0f - 0.7745966692414834f)
                      : (wave == 1) ? 1.0f
                      : (wave == 2) ? (1.0f + 0.7745966692414834f) : 0.0f;  // node+1
    const _Float16* hbase  = pack + (isic ? 49152 : 0);          // pipe*3*16384
    const _Float16* l0base = pack + 98304 + (isic ? 4096 : 0);
    const float* btabp = btab + (isic ? 512 : 0);
    const float* wop   = woutb + (isic ? 128 : 0);
    const float  boutv = isic ? icBout[0] : dpBout[0];
    _Float16* actw = act + wave * 8192;

    // swizzle constants
    const int rm3  = (3 * l15) & 15;    // A-frag reads: row = mt*16+l15
    const int rm3p = (3 * lane) & 15;   // phase-4 reads: row = lane
    const int nb   = l15 & 7;
    int m3w[4];
    #pragma unroll
    for (int j = 0; j < 4; j++) m3w[j] = (12 * s + 3 * j) & 15;

    auto epilogue = [&](v4f* acc, int nt) {
        int c2 = nt * 2 + (l15 >> 3);
        #pragma unroll
        for (int mt = 0; mt < 4; mt++) {
            v4f v = acc[mt];
            float h = fast_tanh(v[0]);
            float D = 1.0f - h * h;
            float o1 = D * v[1], o2 = D * v[2], o3 = D * v[3];
            int base = mt * 2048 + s * 512;          // (mt*16 + s*4)*128
            actw[base +       (((c2 ^ m3w[0]) << 3) | nb)] = (_Float16)h;
            actw[base + 128 + (((c2 ^ m3w[1]) << 3) | nb)] = (_Float16)o1;
            actw[base + 256 + (((c2 ^ m3w[2]) << 3) | nb)] = (_Float16)o2;
            actw[base + 384 + (((c2 ^ m3w[3]) << 3) | nb)] = (_Float16)o3;
        }
    };

    auto run_hidden = [&](const _Float16* bsrc, const float* bias) {
        v8h bfr[8][4];
        #pragma unroll
        for (int nt = 0; nt < 3; nt++)
            #pragma unroll
            for (int kk = 0; kk < 4; kk++)
                bfr[nt][kk] = *(const v8h*)(bsrc + (((kk * 8 + nt) * 64 + lane) << 3));
        v8h afr[4][4];
        #pragma unroll
        for (int mt = 0; mt < 4; mt++)
            #pragma unroll
            for (int kk = 0; kk < 4; kk++)
                afr[mt][kk] = *(const v8h*)(actw + (mt * 16 + l15) * 128 + (((kk * 4 + s) ^ rm3) << 3));
        #pragma unroll
        for (int nt = 0; nt < 8; nt++) {
            if (nt < 5) {
                #pragma unroll
                for (int kk = 0; kk < 4; kk++)
                    bfr[nt + 3][kk] = *(const v8h*)(bsrc + (((kk * 8 + nt + 3) * 64 + lane) << 3));
            }
            float bv = bias[nt * 16 + l15];
            v4f acc[4];
            #pragma unroll
            for (int mt = 0; mt < 4; mt++) { v4f z = {bv, 0.0f, 0.0f, 0.0f}; acc[mt] = z; }
            #pragma unroll
            for (int kk = 0; kk < 4; kk++)
                #pragma unroll
                for (int mt = 0; mt < 4; mt++)
                    acc[mt] = __builtin_amdgcn_mfma_f32_16x16x32_f16(afr[mt][kk], bfr[nt][kk], acc[mt], 0, 0, 0);
            epilogue(acc, nt);
        }
    };

    const int nbat = (N + 15) >> 4;
    int par = 0;
    for (int b = blockIdx.x; b < nbat; b += gridDim.x, par ^= 1) {
        // ---- L0 weight prefetch (hide L2 latency under geometry VALU) ----
        v8h bfr0[8];
        #pragma unroll
        for (int nt = 0; nt < 8; nt++)
            bfr0[nt] = *(const v8h*)(l0base + ((nt * 64 + lane) << 3));

        // ---- per-lane geometry for phys row l15 (redundant across s, waves) ----
        int prow = b * 16 + l15;
        float4 q = (prow < N) ? ((const float4*)tx)[prow] : make_float4(0.f, 1.f, 1.f, 1.f);
        float t = q.x, x = q.y, y = q.z, z = q.w;
        float r2 = x * x + y * y + z * z;
        float r  = sqrtf(r2 + 1e-12f);
        float rinv = 1.0f / r;
        float uc = fminf(1.0f, fmaxf(-1.0f, z * rinv));
        float th = acosf(uc);
        float ph = atan2f(y, x);
        float rinv3 = rinv * rinv * rinv;
        float dacos = -1.0f / sqrtf(fmaxf(1.0f - uc * uc, 1e-30f));
        float dth_dx = dacos * (-x * z * rinv3);
        float dth_dy = dacos * (-y * z * rinv3);
        float dth_dz = dacos * (rinv - z * z * rinv3);
        float rho2 = fmaxf(x * x + y * y, 1e-30f);
        float dph_dx = -y / rho2;
        float dph_dy =  x / rho2;
        float sEnv = -1.0f / (1.0f + r);
        float dsdr =  1.0f / ((1.0f + r) * (1.0f + r));
        float den  = r * r + 0.1f;
        float isq  = 1.0f / sqrtf(den);
        float Aan  = -isq;
        float dAdr = r * isq * isq * isq;
        float xr = x * rinv, yr = y * rinv, zr = z * rinv;

        // distribute (t,r,th,ph) of row p = mt*4 + (l15>>2) to this lane
        float ttv[4], rrv[4], thv[4], phv[4];
        #pragma unroll
        for (int mt = 0; mt < 4; mt++) {
            int src = (lane & 48) + mt * 4 + ((lane >> 2) & 3);
            ttv[mt] = __shfl(t,  src);
            rrv[mt] = __shfl(r,  src);
            thv[mt] = __shfl(th, src);
            phv[mt] = __shfl(ph, src);
        }

        // ---- layer 0: K=32 MFMA (primal inputs + unit tangent seeds in A) ----
        {
            int stream = l15 & 3;
            v8h a0[4];
            #pragma unroll
            for (int mt = 0; mt < 4; mt++) {
                bool p = (stream == 0);
                float e0, e1, e2, e3;
                if (isic) {
                    e0 = p ? rrv[mt] : (stream == 1 ? 1.0f : 0.0f);
                    e1 = p ? thv[mt] : (stream == 2 ? 1.0f : 0.0f);
                    e2 = p ? phv[mt] : (stream == 3 ? 1.0f : 0.0f);
                    e3 = 0.0f;
                } else {
                    float ts = 0.5f * ttv[mt] * node1;
                    e0 = p ? ts : 0.0f;
                    e1 = p ? rrv[mt] : (stream == 1 ? 1.0f : 0.0f);
                    e2 = p ? thv[mt] : (stream == 2 ? 1.0f : 0.0f);
                    e3 = p ? phv[mt] : (stream == 3 ? 1.0f : 0.0f);
                }
                v8h a = {};
                a[0] = (_Float16)e0; a[1] = (_Float16)e1;
                a[2] = (_Float16)e2; a[3] = (_Float16)e3;
                v8h az = {};
                a0[mt] = (s == 0) ? a : az;
            }
            #pragma unroll
            for (int nt = 0; nt < 8; nt++) {
                float bv = btabp[nt * 16 + l15];
                v4f acc[4];
                #pragma unroll
                for (int mt = 0; mt < 4; mt++) { v4f zz = {bv, 0.0f, 0.0f, 0.0f}; acc[mt] = zz; }
                #pragma unroll
                for (int mt = 0; mt < 4; mt++)
                    acc[mt] = __builtin_amdgcn_mfma_f32_16x16x32_f16(a0[mt], bfr0[nt], acc[mt], 0, 0, 0);
                epilogue(acc, nt);
            }
        }

        // ---- hidden layers 1..3 (K=128, weights streamed from L2) ----
        run_hidden(hbase,          btabp + 128);
        run_hidden(hbase + 16384,  btabp + 256);
        run_hidden(hbase + 32768,  btabp + 384);

        // ---- output dot (fp32) ----
        {
            float sum = 0.0f;
            #pragma unroll
            for (int c = 0; c < 16; c++) {
                v8h hv = *(const v8h*)(actw + lane * 128 + ((c ^ rm3p) << 3));
                #pragma unroll
                for (int j = 0; j < 8; j++)
                    sum += (float)hv[j] * wop[c * 8 + j];
            }
            if ((lane & 3) == 0) sum += boutv;
            cbuf[par * 256 + wave * 64 + lane] = sum;
        }
        __syncthreads();

        // ---- quadrature + envelope + chain rule (wave 0, lanes 0-15) ----
        if (wave == 0 && lane < 16) {
            int row = b * 16 + lane;
            if (row < N) {
                const float* cb = cbuf + par * 256;
                float ah = 0.5f * t;
                float vic = cb[192 + (lane << 2) + 0];
                float g0  = cb[192 + (lane << 2) + 1];
                float g1  = cb[192 + (lane << 2) + 2];
                float g2  = cb[192 + (lane << 2) + 3];
                float dsum = 0.f, ds0 = 0.f, ds1 = 0.f, ds2 = 0.f;
                const float wq[3] = {0.5555555555555556f, 0.8888888888888889f, 0.5555555555555556f};
                #pragma unroll
                for (int qq = 0; qq < 3; qq++) {
                    float w = wq[qq];
                    dsum += w * cb[qq * 64 + (lane << 2) + 0];
                    ds0  += w * cb[qq * 64 + (lane << 2) + 1];
                    ds1  += w * cb[qq * 64 + (lane << 2) + 2];
                    ds2  += w * cb[qq * 64 + (lane << 2) + 3];
                }
                float tcv  = vic + ah * dsum;
                float dtc0 = g0 + ah * ds0, dtc1 = g1 + ah * ds1, dtc2 = g2 + ah * ds2;
                float pot = tcv * sEnv + Aan;
                float gx0 = sEnv * dtc0 + tcv * dsdr + dAdr;
                float gx1 = sEnv * dtc1;
                float gx2 = sEnv * dtc2;
                float ax = -(gx0 * xr + gx1 * dth_dx + gx2 * dph_dx);
                float ay = -(gx0 * yr + gx1 * dth_dy + gx2 * dph_dy);
                float az = -(gx0 * zr + gx1 * dth_dz + gx2 * 0.0f);
                outPot[row] = pot;
                outAcc[row * 3 + 0] = ax;
                outAcc[row * 3 + 1] = ay;
                outAcc[row * 3 + 2] = az;
            }
        }
    }
}

extern "C" void kernel_launch(void* const* d_in, const int* in_sizes, int n_in,
                              void* d_out, int out_size, void* d_ws, size_t ws_size,
                              hipStream_t stream) {
    (void)n_in; (void)out_size;
    const float* tx     = (const float*)d_in[0];
    const float* dpWin  = (const float*)d_in[1];
    const float* dpBin  = (const float*)d_in[2];
    const float* dpWh   = (const float*)d_in[3];
    const float* dpBh   = (const float*)d_in[4];
    const float* dpWout = (const float*)d_in[5];
    const float* dpBout = (const float*)d_in[6];
    const float* icWin  = (const float*)d_in[7];
    const float* icBin  = (const float*)d_in[8];
    const float* icWh   = (const float*)d_in[9];
    const float* icBh   = (const float*)d_in[10];
    const float* icWout = (const float*)d_in[11];
    const float* icBout = (const float*)d_in[12];

    int N = in_sizes[0] / 4;
    if (ws_size < (size_t)(106496 * sizeof(_Float16))) return;
    _Float16* pack = (_Float16*)d_ws;
    float* outPot = (float*)d_out;
    float* outAcc = outPot + N;

    pack_weights<<<(106496 + 255) / 256, 256, 0, stream>>>(dpWh, icWh, dpWin, icWin, pack);

    (void)hipFuncSetAttribute(reinterpret_cast<const void*>(node_main),
                              hipFuncAttributeMaxDynamicSharedMemorySize, SMEM_BYTES);
    node_main<<<512, 256, SMEM_BYTES, stream>>>(tx,
        dpBin, dpBh, dpWout, dpBout,
        icBin, icBh, icWout, icBout,
        pack, outPot, outAcc, N);
}

// Round 3
// 652.780 us; speedup vs baseline: 1.9051x; 1.1173x over previous
//
#include <hip/hip_runtime.h>

typedef _Float16 v8h __attribute__((ext_vector_type(8)));
typedef float    v4f __attribute__((ext_vector_type(4)));

__device__ __forceinline__ float fast_tanh(float x) {
    float e = __expf(2.0f * x);
    return 1.0f - 2.0f / (e + 1.0f);
}

// ---------------------------------------------------------------------------
// pack layout (halves), nt-major so consumption is sequential 4KB chunks:
//  hidden: idx = ((((pipe*3+l)*8 + nt)*4 + kk)*64 + lane)*8 + j     [0, 98304)
//          value = Wh[l][k = kk*32 + (lane>>4)*8 + j][n = nt*16 + (lane&15)]
//  L0:     98304 + ((pipe*8 + nt)*64 + lane)*8 + j                  [98304, 106496)
//          value = Win[k = (lane>>4)*8+j][n] for k < in_dim else 0
// ---------------------------------------------------------------------------
__global__ void pack_weights(const float* __restrict__ dpWh,
                             const float* __restrict__ icWh,
                             const float* __restrict__ dpWin,
                             const float* __restrict__ icWin,
                             _Float16* __restrict__ out) {
    int idx = blockIdx.x * 256 + threadIdx.x;
    if (idx < 98304) {
        int j    = idx & 7;
        int lane = (idx >> 3) & 63;
        int kk   = (idx >> 9) & 3;
        int nt   = (idx >> 11) & 7;
        int lp   = idx >> 14;           // 0..5
        int l    = lp % 3;
        const float* src = (lp >= 3) ? icWh : dpWh;
        int k = kk * 32 + (lane >> 4) * 8 + j;
        int n = nt * 16 + (lane & 15);
        out[idx] = (_Float16)src[(l * 128 + k) * 128 + n];
    } else if (idx < 106496) {
        int f    = idx - 98304;
        int j    = f & 7;
        int lane = (f >> 3) & 63;
        int nt   = (f >> 9) & 7;
        int pipe = (f >> 12) & 1;
        int k = (lane >> 4) * 8 + j;
        int n = nt * 16 + (lane & 15);
        float v = 0.0f;
        if (pipe == 0) { if (k < 4) v = dpWin[k * 128 + n]; }
        else           { if (k < 3) v = icWin[k * 128 + n]; }
        out[idx] = (_Float16)v;
    }
}

// LDS (dynamic, 76800 B -> 2 blocks/CU):
//   [0,     69632)  act  : 4 waves x 64 rows x 136 halves (8-half row pad, linear)
//   [69632, 73728)  btab : float[2][4][128]  ({Bin, Bh0..2} per pipe)
//   [73728, 74752)  woutb: float[2][128]
//   [74752, 76800)  cbuf : float[2][4][64]   (ping-pong by batch parity)
#define SMEM_BYTES 76800
#define ROWH 136   // halves per act row

__launch_bounds__(256, 2)
__global__ void node_main(const float* __restrict__ tx,
                          const float* __restrict__ dpBin, const float* __restrict__ dpBh,
                          const float* __restrict__ dpWout, const float* __restrict__ dpBout,
                          const float* __restrict__ icBin, const float* __restrict__ icBh,
                          const float* __restrict__ icWout, const float* __restrict__ icBout,
                          const _Float16* __restrict__ pack,
                          float* __restrict__ outPot, float* __restrict__ outAcc,
                          int N)
{
    extern __shared__ char smem[];
    _Float16* act  = (_Float16*)smem;
    float* btab  = (float*)(smem + 69632);
    float* woutb = (float*)(smem + 73728);
    float* cbuf  = (float*)(smem + 74752);

    const int tid  = threadIdx.x;
    const int wave = tid >> 6;
    const int lane = tid & 63;
    const int l15  = lane & 15;
    const int s    = lane >> 4;

    if (tid < 128) {
        btab[tid]        = dpBin[tid];
        btab[512 + tid]  = icBin[tid];
        woutb[tid]       = dpWout[tid];
        woutb[128 + tid] = icWout[tid];
    }
    for (int i = tid; i < 384; i += 256) {
        btab[128 + i] = dpBh[i];
        btab[640 + i] = icBh[i];
    }
    __syncthreads();

    const bool isic = (wave == 3);
    const float node1 = (wave == 0) ? (1.0f - 0.7745966692414834f)
                      : (wave == 1) ? 1.0f
                      : (wave == 2) ? (1.0f + 0.7745966692414834f) : 0.0f;  // node+1
    const _Float16* hbase  = pack + (isic ? 49152 : 0);          // pipe*3*16384
    const _Float16* l0base = pack + 98304 + (isic ? 4096 : 0);
    const float* btabp = btab + (isic ? 512 : 0);
    const float* wop   = woutb + (isic ? 128 : 0);
    const float  boutv = isic ? icBout[0] : dpBout[0];
    _Float16* actw = act + wave * (64 * ROWH);

    // static per-lane bases (all further addressing is compile-time immediates)
    _Float16*       ep_base  = actw + s * (4 * ROWH) + l15;   // epilogue writes: + q*ROWH + mt*16*ROWH + nt*16
    const _Float16* afr_base = actw + l15 * ROWH + s * 8;     // afr reads: + mt*16*ROWH + kk*32
    const _Float16* ph4_base = actw + lane * ROWH;            // phase-4 reads: + c*8

    auto epilogue = [&](v4f* acc, int nt) {
        #pragma unroll
        for (int mt = 0; mt < 4; mt++) {
            v4f v = acc[mt];
            float h = fast_tanh(v[0]);
            float D = 1.0f - h * h;
            _Float16* p = ep_base + mt * (16 * ROWH) + nt * 16;
            p[0 * ROWH] = (_Float16)h;
            p[1 * ROWH] = (_Float16)(D * v[1]);
            p[2 * ROWH] = (_Float16)(D * v[2]);
            p[3 * ROWH] = (_Float16)(D * v[3]);
        }
    };

    // persistent B ring: 4 slots x 4 kk, lookahead 4, consume-then-refill
    v8h ring[4][4];
    {
        const _Float16* rl = hbase + (lane << 3);
        #pragma unroll
        for (int sl = 0; sl < 4; sl++)
            #pragma unroll
            for (int kk = 0; kk < 4; kk++)
                ring[sl][kk] = *(const v8h*)(rl + ((sl * 4 + kk) << 9));
    }

    // one hidden layer; cur = this layer's blocks (for refills 4..7),
    // nxt = next layer's blocks (refills 0..3 of the following layer)
    auto run_hidden = [&](const _Float16* cur, const _Float16* nxt, const float* bias) {
        const _Float16* cl = cur + (lane << 3);
        const _Float16* nl = nxt + (lane << 3);
        v8h afr[4][4];
        #pragma unroll
        for (int mt = 0; mt < 4; mt++)
            #pragma unroll
            for (int kk = 0; kk < 4; kk++)
                afr[mt][kk] = *(const v8h*)(afr_base + mt * (16 * ROWH) + kk * 32);
        #pragma unroll
        for (int nt = 0; nt < 8; nt++) {
            int slot = nt & 3;
            float bv = bias[nt * 16 + l15];
            v4f acc[4];
            #pragma unroll
            for (int mt = 0; mt < 4; mt++) { v4f z = {bv, 0.0f, 0.0f, 0.0f}; acc[mt] = z; }
            #pragma unroll
            for (int kk = 0; kk < 4; kk++)
                #pragma unroll
                for (int mt = 0; mt < 4; mt++)
                    acc[mt] = __builtin_amdgcn_mfma_f32_16x16x32_f16(afr[mt][kk], ring[slot][kk], acc[mt], 0, 0, 0);
            // refill the slot just consumed (used again 4 nt-steps / next layer later)
            #pragma unroll
            for (int kk = 0; kk < 4; kk++) {
                if (nt < 4) ring[slot][kk] = *(const v8h*)(cl + (((nt + 4) * 4 + kk) << 9));
                else        ring[slot][kk] = *(const v8h*)(nl + (((nt - 4) * 4 + kk) << 9));
            }
            epilogue(acc, nt);
        }
    };

    const int nbat = (N + 15) >> 4;
    int par = 0;
    for (int b = blockIdx.x; b < nbat; b += gridDim.x, par ^= 1) {
        // ---- L0 weight prefetch (hidden under geometry VALU) ----
        v8h bfr0[8];
        {
            const _Float16* l0l = l0base + (lane << 3);
            #pragma unroll
            for (int nt = 0; nt < 8; nt++)
                bfr0[nt] = *(const v8h*)(l0l + (nt << 9));
        }

        // ---- per-lane geometry for phys row l15 (redundant across s, waves) ----
        int prow = b * 16 + l15;
        float4 q = (prow < N) ? ((const float4*)tx)[prow] : make_float4(0.f, 1.f, 1.f, 1.f);
        float t = q.x, x = q.y, y = q.z, z = q.w;
        float r2 = x * x + y * y + z * z;
        float r  = sqrtf(r2 + 1e-12f);
        float rinv = 1.0f / r;
        float uc = fminf(1.0f, fmaxf(-1.0f, z * rinv));
        float th = acosf(uc);
        float ph = atan2f(y, x);
        float rinv3 = rinv * rinv * rinv;
        float dacos = -1.0f / sqrtf(fmaxf(1.0f - uc * uc, 1e-30f));
        float dth_dx = dacos * (-x * z * rinv3);
        float dth_dy = dacos * (-y * z * rinv3);
        float dth_dz = dacos * (rinv - z * z * rinv3);
        float rho2 = fmaxf(x * x + y * y, 1e-30f);
        float dph_dx = -y / rho2;
        float dph_dy =  x / rho2;
        float sEnv = -1.0f / (1.0f + r);
        float dsdr =  1.0f / ((1.0f + r) * (1.0f + r));
        float den  = r * r + 0.1f;
        float isq  = 1.0f / sqrtf(den);
        float Aan  = -isq;
        float dAdr = r * isq * isq * isq;
        float xr = x * rinv, yr = y * rinv, zr = z * rinv;

        // distribute (t,r,th,ph) of phys row p = mt*4 + (l15>>2) to this lane
        float ttv[4], rrv[4], thv[4], phv[4];
        #pragma unroll
        for (int mt = 0; mt < 4; mt++) {
            int src = (lane & 48) + mt * 4 + ((lane >> 2) & 3);
            ttv[mt] = __shfl(t,  src);
            rrv[mt] = __shfl(r,  src);
            thv[mt] = __shfl(th, src);
            phv[mt] = __shfl(ph, src);
        }

        // ---- layer 0: K=32 MFMA (primal inputs + unit tangent seeds in A) ----
        {
            int stream = l15 & 3;
            v8h a0[4];
            #pragma unroll
            for (int mt = 0; mt < 4; mt++) {
                bool p = (stream == 0);
                float e0, e1, e2, e3;
                if (isic) {
                    e0 = p ? rrv[mt] : (stream == 1 ? 1.0f : 0.0f);
                    e1 = p ? thv[mt] : (stream == 2 ? 1.0f : 0.0f);
                    e2 = p ? phv[mt] : (stream == 3 ? 1.0f : 0.0f);
                    e3 = 0.0f;
                } else {
                    float ts = 0.5f * ttv[mt] * node1;
                    e0 = p ? ts : 0.0f;
                    e1 = p ? rrv[mt] : (stream == 1 ? 1.0f : 0.0f);
                    e2 = p ? thv[mt] : (stream == 2 ? 1.0f : 0.0f);
                    e3 = p ? phv[mt] : (stream == 3 ? 1.0f : 0.0f);
                }
                v8h a = {};
                a[0] = (_Float16)e0; a[1] = (_Float16)e1;
                a[2] = (_Float16)e2; a[3] = (_Float16)e3;
                v8h az = {};
                a0[mt] = (s == 0) ? a : az;
            }
            #pragma unroll
            for (int nt = 0; nt < 8; nt++) {
                float bv = btabp[nt * 16 + l15];
                v4f acc[4];
                #pragma unroll
                for (int mt = 0; mt < 4; mt++) { v4f zz = {bv, 0.0f, 0.0f, 0.0f}; acc[mt] = zz; }
                #pragma unroll
                for (int mt = 0; mt < 4; mt++)
                    acc[mt] = __builtin_amdgcn_mfma_f32_16x16x32_f16(a0[mt], bfr0[nt], acc[mt], 0, 0, 0);
                epilogue(acc, nt);
            }
        }

        // ---- hidden layers (K=128); ring streams h1->h2->h3->(next batch h1) ----
        run_hidden(hbase,          hbase + 16384, btabp + 128);
        run_hidden(hbase + 16384,  hbase + 32768, btabp + 256);
        run_hidden(hbase + 32768,  hbase,         btabp + 384);

        // ---- output dot (fp32) ----
        {
            float sum = 0.0f;
            #pragma unroll
            for (int c = 0; c < 16; c++) {
                v8h hv = *(const v8h*)(ph4_base + c * 8);
                #pragma unroll
                for (int j = 0; j < 8; j++)
                    sum += (float)hv[j] * wop[c * 8 + j];
            }
            if ((lane & 3) == 0) sum += boutv;
            cbuf[par * 256 + wave * 64 + lane] = sum;
        }
        __syncthreads();

        // ---- quadrature + envelope + chain rule (wave 0, lanes 0-15) ----
        if (wave == 0 && lane < 16) {
            int row = b * 16 + lane;
            if (row < N) {
                const float* cb = cbuf + par * 256;
                float ah = 0.5f * t;
                float vic = cb[192 + (lane << 2) + 0];
                float g0  = cb[192 + (lane << 2) + 1];
                float g1  = cb[192 + (lane << 2) + 2];
                float g2  = cb[192 + (lane << 2) + 3];
                float dsum = 0.f, ds0 = 0.f, ds1 = 0.f, ds2 = 0.f;
                const float wq[3] = {0.5555555555555556f, 0.8888888888888889f, 0.5555555555555556f};
                #pragma unroll
                for (int qq = 0; qq < 3; qq++) {
                    float w = wq[qq];
                    dsum += w * cb[qq * 64 + (lane << 2) + 0];
                    ds0  += w * cb[qq * 64 + (lane << 2) + 1];
                    ds1  += w * cb[qq * 64 + (lane << 2) + 2];
                    ds2  += w * cb[qq * 64 + (lane << 2) + 3];
                }
                float tcv  = vic + ah * dsum;
                float dtc0 = g0 + ah * ds0, dtc1 = g1 + ah * ds1, dtc2 = g2 + ah * ds2;
                float pot = tcv * sEnv + Aan;
                float gx0 = sEnv * dtc0 + tcv * dsdr + dAdr;
                float gx1 = sEnv * dtc1;
                float gx2 = sEnv * dtc2;
                float ax = -(gx0 * xr + gx1 * dth_dx + gx2 * dph_dx);
                float ay = -(gx0 * yr + gx1 * dth_dy + gx2 * dph_dy);
                float az = -(gx0 * zr + gx1 * dth_dz + gx2 * 0.0f);
                outPot[row] = pot;
                outAcc[row * 3 + 0] = ax;
                outAcc[row * 3 + 1] = ay;
                outAcc[row * 3 + 2] = az;
            }
        }
    }
}

extern "C" void kernel_launch(void* const* d_in, const int* in_sizes, int n_in,
                              void* d_out, int out_size, void* d_ws, size_t ws_size,
                              hipStream_t stream) {
    (void)n_in; (void)out_size;
    const float* tx     = (const float*)d_in[0];
    const float* dpWin  = (const float*)d_in[1];
    const float* dpBin  = (const float*)d_in[2];
    const float* dpWh   = (const float*)d_in[3];
    const float* dpBh   = (const float*)d_in[4];
    const float* dpWout = (const float*)d_in[5];
    const float* dpBout = (const float*)d_in[6];
    const float* icWin  = (const float*)d_in[7];
    const float* icBin  = (const float*)d_in[8];
    const float* icWh   = (const float*)d_in[9];
    const float* icBh   = (const float*)d_in[10];
    const float* icWout = (const float*)d_in[11];
    const float* icBout = (const float*)d_in[12];

    int N = in_sizes[0] / 4;
    if (ws_size < (size_t)(106496 * sizeof(_Float16))) return;
    _Float16* pack = (_Float16*)d_ws;
    float* outPot = (float*)d_out;
    float* outAcc = outPot + N;

    pack_weights<<<(106496 + 255) / 256, 256, 0, stream>>>(dpWh, icWh, dpWin, icWin, pack);

    (void)hipFuncSetAttribute(reinterpret_cast<const void*>(node_main),
                              hipFuncAttributeMaxDynamicSharedMemorySize, SMEM_BYTES);
    node_main<<<512, 256, SMEM_BYTES, stream>>>(tx,
        dpBin, dpBh, dpWout, dpBout,
        icBin, icBh, icWout, icBout,
        pack, outPot, outAcc, N);
}